// Round 6
// baseline (367.298 us; speedup 1.0000x reference)
//
#include <hip/hip_runtime.h>

// Problem constants (match reference)
#define BB 8
#define NN 65536
#define DD 192
#define EPSV 1e-5f
#define NPTS (BB * NN)               // 524288

#define CAX 24                       // coarse cells per axis (cell = 8^3 voxels)
#define CELLS_B (CAX * CAX * CAX)    // 13824 cells per batch
#define TCELLS (BB * CELLS_B)        // 110592 (batch-major keys)
#define SCAN_BLOCKS (TCELLS / 256)   // 432 exact
#define MBLK 1024                    // main-kernel blocks (2 pts/thread)

// Journal: R4 win was the XCD batch-affinity swizzle (not atomics). Kernel
// side ~95 us vs ~40 us issue+BW arithmetic -> MSHR/miss-count bound on the
// random gather. R6: counting-sort by 8^3 cell WITH batch->XCD affinity in
// EVERY pass (R2/R3 lacked this -> scatter/main lines bounced cross-XCD).
// Main writes outputs directly by original index: random 16 B writes stay in
// the home XCD's L2 (byte-granular dirty tracking), written back once.
//
// d_ws layout (u32 units):
//   [0, TCELLS)          hist / cursor
//   [TCELLS, +512)       scan block sums
//   PART0  partial[MBLK] (f32 block loss partials)
//   REC0   rec[NPTS] float4 = (Fx_full, Fy_full, Fz_full, bits(orig_t))
#define PART0 (TCELLS + 512)
#define REC0  (PART0 + MBLK)

__device__ __forceinline__ void point_key(
    const float* __restrict__ pss, const float* __restrict__ first,
    const float* __restrict__ coef, const float* __restrict__ maxl,
    int t, float& Fx, float& Fy, float& Fz, int& key)
{
    const int b = t >> 16;
    const int n = t & (NN - 1);
    const float* pb = pss + (size_t)b * 3 * NN + n;
    const float px = pb[0];
    const float py = pb[NN];
    const float pz = pb[2 * NN];

    Fx = fmaxf(fminf((px - first[3*b+0]) * coef[3*b+0], maxl[3*b+0]), 0.0f);
    Fy = fmaxf(fminf((py - first[3*b+1]) * coef[3*b+1], maxl[3*b+1]), 0.0f);
    Fz = fmaxf(fminf((pz - first[3*b+2]) * coef[3*b+2], maxl[3*b+2]), 0.0f);

    const int cx = (int)floorf(Fx) >> 3;
    const int cy = (int)floorf(Fy) >> 3;
    const int cz = (int)floorf(Fz) >> 3;
    key = ((b * CAX + cx) * CAX + cy) * CAX + cz;   // batch-major
}

// Pass A: per-cell histogram (batch->XCD affinity)
__global__ __launch_bounds__(256) void hist_kernel(
    const float* __restrict__ pss, const float* __restrict__ first,
    const float* __restrict__ coef, const float* __restrict__ maxl,
    unsigned* __restrict__ hist)
{
    const int vb = ((int)blockIdx.x & 7) * 256 + ((int)blockIdx.x >> 3);
    const int t  = vb * 256 + (int)threadIdx.x;
    float Fx, Fy, Fz; int key;
    point_key(pss, first, coef, maxl, t, Fx, Fy, Fz, key);
    atomicAdd(&hist[key], 1u);
}

// Pass B: 3-kernel exclusive scan over TCELLS
__global__ __launch_bounds__(256) void scan1_kernel(unsigned* __restrict__ hist,
                                                    unsigned* __restrict__ bsum)
{
    __shared__ unsigned s[256];
    const int tid = threadIdx.x;
    const int i = blockIdx.x * 256 + tid;
    const unsigned v = hist[i];
    s[tid] = v;
    __syncthreads();
    #pragma unroll
    for (int off = 1; off < 256; off <<= 1) {
        unsigned tv = (tid >= off) ? s[tid - off] : 0u;
        __syncthreads();
        s[tid] += tv;
        __syncthreads();
    }
    hist[i] = s[tid] - v;
    if (tid == 255) bsum[blockIdx.x] = s[255];
}

__global__ __launch_bounds__(512) void scan2_kernel(unsigned* __restrict__ bsum)
{
    __shared__ unsigned s[512];
    const int tid = threadIdx.x;
    const unsigned v = (tid < SCAN_BLOCKS) ? bsum[tid] : 0u;
    s[tid] = v;
    __syncthreads();
    #pragma unroll
    for (int off = 1; off < 512; off <<= 1) {
        unsigned tv = (tid >= off) ? s[tid - off] : 0u;
        __syncthreads();
        s[tid] += tv;
        __syncthreads();
    }
    if (tid < SCAN_BLOCKS) bsum[tid] = s[tid] - v;
}

__global__ __launch_bounds__(256) void scan3_kernel(unsigned* __restrict__ hist,
                                                    const unsigned* __restrict__ bsum)
{
    const int i = blockIdx.x * 256 + threadIdx.x;
    hist[i] += bsum[blockIdx.x];
}

// Pass C: scatter 16 B records into cell order (affinity: random writes stay
// in the home XCD's L2 region, ~1 MB/batch)
__global__ __launch_bounds__(256) void scatter_kernel(
    const float* __restrict__ pss, const float* __restrict__ first,
    const float* __restrict__ coef, const float* __restrict__ maxl,
    unsigned* __restrict__ cursor, float4* __restrict__ rec)
{
    const int vb = ((int)blockIdx.x & 7) * 256 + ((int)blockIdx.x >> 3);
    const int t  = vb * 256 + (int)threadIdx.x;
    float Fx, Fy, Fz; int key;
    point_key(pss, first, coef, maxl, t, Fx, Fy, Fz, key);
    const unsigned pos = atomicAdd(&cursor[key], 1u);
    rec[pos] = make_float4(Fx, Fy, Fz, __uint_as_float((unsigned)t));
}

// Pass D: sorted gather + compute; direct scatter-out by original index.
__global__ __launch_bounds__(256) void main_kernel(
    const float* __restrict__ grid,
    const float4* __restrict__ rec,
    float* __restrict__ dss, float* __restrict__ nss,
    float* __restrict__ partial)
{
    const int vb = ((int)blockIdx.x & 7) * 128 + ((int)blockIdx.x >> 3);
    const int i0 = vb * 512 + (int)threadIdx.x;     // point A; B = i0 + 256
    const int b  = i0 >> 16;                        // sorted order is batch-major

    const float4 rA = rec[i0];
    const float4 rB = rec[i0 + 256];
    const unsigned tA = __float_as_uint(rA.w);
    const unsigned tB = __float_as_uint(rB.w);

    const int bxA = (int)floorf(rA.x), byA = (int)floorf(rA.y), bzA = (int)floorf(rA.z);
    const int bxB = (int)floorf(rB.x), byB = (int)floorf(rB.y), bzB = (int)floorf(rB.z);
    const float fxA = rA.x - (float)bxA, fyA = rA.y - (float)byA, fzA = rA.z - (float)bzA;
    const float fxB = rB.x - (float)bxB, fyB = rB.y - (float)byB, fzB = rB.z - (float)bzB;

    const float* gbase = grid + (size_t)b * DD * DD * DD;
    const float* gA = gbase + ((size_t)bxA * DD + byA) * DD + bzA;
    const float* gB = gbase + ((size_t)bxB * DD + byB) * DD + bzB;

    const float a000 = gA[0];
    const float a001 = gA[1];
    const float a010 = gA[DD];
    const float a011 = gA[DD + 1];
    const float a100 = gA[DD * DD];
    const float a101 = gA[DD * DD + 1];
    const float a110 = gA[DD * DD + DD];
    const float a111 = gA[DD * DD + DD + 1];
    const float b000 = gB[0];
    const float b001 = gB[1];
    const float b010 = gB[DD];
    const float b011 = gB[DD + 1];
    const float b100 = gB[DD * DD];
    const float b101 = gB[DD * DD + 1];
    const float b110 = gB[DD * DD + DD];
    const float b111 = gB[DD * DD + DD + 1];

    // ---------- point A ----------
    float wx0 = 1.0f - fxA, wx1 = fxA;
    float wy0 = 1.0f - fyA, wy1 = fyA;
    float wz0 = 1.0f - fzA, wz1 = fzA;
    float d00 = wz0 * a000 + wz1 * a001;
    float d01 = wz0 * a010 + wz1 * a011;
    float d10 = wz0 * a100 + wz1 * a101;
    float d11 = wz0 * a110 + wz1 * a111;
    const float dvA = wx0 * (wy0 * d00 + wy1 * d01) + wx1 * (wy0 * d10 + wy1 * d11);

    const float nzA = wx0 * (wy0 * (a001 - a000) + wy1 * (a011 - a010))
                    + wx1 * (wy0 * (a101 - a100) + wy1 * (a111 - a110));
    const float nyA = wx0 * (wz0 * (a010 - a000) + wz1 * (a011 - a001))
                    + wx1 * (wz0 * (a110 - a100) + wz1 * (a111 - a101));
    const float nxA = wy0 * (wz0 * (a100 - a000) + wz1 * (a101 - a001))
                    + wy1 * (wz0 * (a110 - a010) + wz1 * (a111 - a011));
    const float invA = 1.0f / fmaxf(sqrtf(nxA*nxA + nyA*nyA + nzA*nzA), EPSV);

    // ---------- point B ----------
    wx0 = 1.0f - fxB; wx1 = fxB;
    wy0 = 1.0f - fyB; wy1 = fyB;
    wz0 = 1.0f - fzB; wz1 = fzB;
    d00 = wz0 * b000 + wz1 * b001;
    d01 = wz0 * b010 + wz1 * b011;
    d10 = wz0 * b100 + wz1 * b101;
    d11 = wz0 * b110 + wz1 * b111;
    const float dvB = wx0 * (wy0 * d00 + wy1 * d01) + wx1 * (wy0 * d10 + wy1 * d11);

    const float nzB = wx0 * (wy0 * (b001 - b000) + wy1 * (b011 - b010))
                    + wx1 * (wy0 * (b101 - b100) + wy1 * (b111 - b110));
    const float nyB = wx0 * (wz0 * (b010 - b000) + wz1 * (b011 - b001))
                    + wx1 * (wz0 * (b110 - b100) + wz1 * (b111 - b101));
    const float nxB = wy0 * (wz0 * (b100 - b000) + wz1 * (b101 - b001))
                    + wy1 * (wz0 * (b110 - b010) + wz1 * (b111 - b011));
    const float invB = 1.0f / fmaxf(sqrtf(nxB*nxB + nyB*nyB + nzB*nzB), EPSV);

    // direct scatter-out: random 16 B writes within this batch's output
    // region (~3.4 MB) -> home XCD L2, byte-granular dirty writeback
    dss[tA] = dvA;
    dss[tB] = dvB;
    float* npA = nss + (size_t)tA * 3;
    npA[0] = nxA * invA;
    npA[1] = nyA * invA;
    npA[2] = nzA * invA;
    float* npB = nss + (size_t)tB * 3;
    npB[0] = nxB * invB;
    npB[1] = nyB * invB;
    npB[2] = nzB * invB;

    float lp = fminf(dvA, 0.0f) + fminf(dvB, 0.0f);
    #pragma unroll
    for (int off = 32; off > 0; off >>= 1)
        lp += __shfl_down(lp, off, 64);
    __shared__ float wsum[4];
    const int wid = threadIdx.x >> 6;
    if ((threadIdx.x & 63) == 0) wsum[wid] = lp;
    __syncthreads();
    if (threadIdx.x == 0)
        partial[blockIdx.x] = wsum[0] + wsum[1] + wsum[2] + wsum[3];
}

// 1024 partials -> loss = -sum
__global__ __launch_bounds__(256) void loss_reduce_kernel(
    const float* __restrict__ partial, float* __restrict__ loss)
{
    const int tid = threadIdx.x;
    float s = partial[tid] + partial[tid + 256]
            + partial[tid + 512] + partial[tid + 768];
    #pragma unroll
    for (int off = 32; off > 0; off >>= 1)
        s += __shfl_down(s, off, 64);
    __shared__ float wsum[4];
    const int wid = tid >> 6;
    if ((tid & 63) == 0) wsum[wid] = s;
    __syncthreads();
    if (tid == 0)
        loss[0] = -(wsum[0] + wsum[1] + wsum[2] + wsum[3]);
}

extern "C" void kernel_launch(void* const* d_in, const int* in_sizes, int n_in,
                              void* d_out, int out_size, void* d_ws, size_t ws_size,
                              hipStream_t stream) {
    const float* pss   = (const float*)d_in[0];
    const float* grid  = (const float*)d_in[1];
    const float* first = (const float*)d_in[2];
    const float* coef  = (const float*)d_in[3];
    const float* maxl  = (const float*)d_in[4];

    float* out  = (float*)d_out;
    float* dss  = out;                          // B*N
    float* nss  = out + (size_t)BB * NN;        // B*N*3
    float* loss = out + (size_t)4 * BB * NN;    // 1

    unsigned* ws      = (unsigned*)d_ws;
    unsigned* hist    = ws;                     // TCELLS
    unsigned* bsum    = ws + TCELLS;            // 512
    float*    partial = (float*)(ws + PART0);   // MBLK
    float4*   rec     = (float4*)(ws + REC0);   // NPTS float4

    hipMemsetAsync(hist, 0, (size_t)TCELLS * sizeof(unsigned), stream);

    const int threads = 256;
    const int pblocks = NPTS / threads;         // 2048

    hist_kernel<<<pblocks, threads, 0, stream>>>(pss, first, coef, maxl, hist);
    scan1_kernel<<<SCAN_BLOCKS, 256, 0, stream>>>(hist, bsum);
    scan2_kernel<<<1, 512, 0, stream>>>(bsum);
    scan3_kernel<<<SCAN_BLOCKS, 256, 0, stream>>>(hist, bsum);
    scatter_kernel<<<pblocks, threads, 0, stream>>>(pss, first, coef, maxl, hist, rec);
    main_kernel<<<MBLK, 256, 0, stream>>>(grid, rec, dss, nss, partial);
    loss_reduce_kernel<<<1, 256, 0, stream>>>(partial, loss);
}

// Round 7
// 356.614 us; speedup vs baseline: 1.0300x; 1.0300x over previous
//
#include <hip/hip_runtime.h>

// Problem constants (match reference)
#define BB 8
#define NN 65536
#define DD 192
#define EPSV 1e-5f
#define NPTS (BB * NN)       // 524288
#define NBLK 1024            // main-kernel blocks (2 points/thread)

// d_out layout: dss [B*N] | nss [B*N*3] | loss [1]
// d_ws: partial[NBLK] floats | sink (1 u32 @ +4096 B)
//
// Journal:
//  R1-R3: dur_us carries ~210 us fixed harness restore/poison tax.
//  R4 win (-55): XCD batch-affinity swizzle (NOT atomics - falsified in R5).
//  R6: cell-sort again net-negative. Closed-form reason: 1 pt per ~106
//    voxels -> mean 1.19 line-touches/line -> perfect sort saves only ~1.7x
//    misses (~18 us BW) < sort cost. Sorting cannot win at this sparsity.
//  R7 experiment: ws-poison (906 MB) evicts L3 every iteration, so gather
//    misses pay ~900cyc HBM latency through ~64 MSHRs/CU. Grid (226 MB) fits
//    L3 (256 MB): stream-warm it first (~36 us), gathers then hit L3
//    (~half latency -> ~2x MSHR throughput).

// ---- Pass 0: stream the whole grid through L2/L3 (coalesced, discard) ----
__global__ __launch_bounds__(256) void warm_kernel(
    const uint4* __restrict__ grid4, unsigned* __restrict__ sink)
{
    const int tid = blockIdx.x * blockDim.x + threadIdx.x;   // 524288 threads
    unsigned acc = 0;
    // 8*192^3 floats = 14,155,776 uint4 = 27 * 524288  (exact)
    #pragma unroll
    for (int it = 0; it < 27; ++it) {
        const uint4 v = grid4[(size_t)it * (NPTS) + tid];
        acc |= v.x | v.y | v.z | v.w;
    }
    // opaque use so the loads cannot be eliminated; never actually stores
    if (acc == 0x12345677u && tid == 1u << 30) sink[0] = acc;
}

// ---- Pass 1: gather + trilinear + normals + block loss partials ----
__global__ __launch_bounds__(256) void tri_sdf_kernel(
    const float* __restrict__ pss,     // [B,3,N]
    const float* __restrict__ grid,    // [B,D,D,D]
    const float* __restrict__ first,   // [B,3]
    const float* __restrict__ coef,    // [B,3]
    const float* __restrict__ maxl,    // [B,3]
    float* __restrict__ dss,           // [B*N]
    float* __restrict__ nss,           // [B*N,3]
    float* __restrict__ partial)       // [NBLK]
{
    // XCD batch affinity: batch == blockIdx & 7 (round-robin block->XCD).
    const int vb = ((int)blockIdx.x & 7) * 128 + ((int)blockIdx.x >> 3);
    const int t0 = vb * 512 + (int)threadIdx.x;     // point A; point B = t0+256
    const int b  = t0 >> 16;
    const int n0 = t0 & (NN - 1);

    const float* pb = pss + (size_t)b * 3 * NN + n0;
    const float pxA = pb[0],        pxB = pb[256];
    const float pyA = pb[NN],       pyB = pb[NN + 256];
    const float pzA = pb[2 * NN],   pzB = pb[2 * NN + 256];

    const float f0x = first[3*b+0], f0y = first[3*b+1], f0z = first[3*b+2];
    const float cfx = coef[3*b+0],  cfy = coef[3*b+1],  cfz = coef[3*b+2];
    const float mlx = maxl[3*b+0],  mly = maxl[3*b+1],  mlz = maxl[3*b+2];

    const float FxA = fmaxf(fminf((pxA - f0x) * cfx, mlx), 0.0f);
    const float FyA = fmaxf(fminf((pyA - f0y) * cfy, mly), 0.0f);
    const float FzA = fmaxf(fminf((pzA - f0z) * cfz, mlz), 0.0f);
    const float FxB = fmaxf(fminf((pxB - f0x) * cfx, mlx), 0.0f);
    const float FyB = fmaxf(fminf((pyB - f0y) * cfy, mly), 0.0f);
    const float FzB = fmaxf(fminf((pzB - f0z) * cfz, mlz), 0.0f);

    const int bxA = (int)floorf(FxA), byA = (int)floorf(FyA), bzA = (int)floorf(FzA);
    const int bxB = (int)floorf(FxB), byB = (int)floorf(FyB), bzB = (int)floorf(FzB);
    const float fxA = FxA - (float)bxA, fyA = FyA - (float)byA, fzA = FzA - (float)bzA;
    const float fxB = FxB - (float)bxB, fyB = FyB - (float)byB, fzB = FzB - (float)bzB;

    const float* gbase = grid + (size_t)b * DD * DD * DD;
    const float* gA = gbase + ((size_t)bxA * DD + byA) * DD + bzA;
    const float* gB = gbase + ((size_t)bxB * DD + byB) * DD + bzB;

    const float a000 = gA[0];
    const float a001 = gA[1];
    const float a010 = gA[DD];
    const float a011 = gA[DD + 1];
    const float a100 = gA[DD * DD];
    const float a101 = gA[DD * DD + 1];
    const float a110 = gA[DD * DD + DD];
    const float a111 = gA[DD * DD + DD + 1];
    const float b000 = gB[0];
    const float b001 = gB[1];
    const float b010 = gB[DD];
    const float b011 = gB[DD + 1];
    const float b100 = gB[DD * DD];
    const float b101 = gB[DD * DD + 1];
    const float b110 = gB[DD * DD + DD];
    const float b111 = gB[DD * DD + DD + 1];

    // ---------- point A ----------
    float wx0 = 1.0f - fxA, wx1 = fxA;
    float wy0 = 1.0f - fyA, wy1 = fyA;
    float wz0 = 1.0f - fzA, wz1 = fzA;
    float d00 = wz0 * a000 + wz1 * a001;
    float d01 = wz0 * a010 + wz1 * a011;
    float d10 = wz0 * a100 + wz1 * a101;
    float d11 = wz0 * a110 + wz1 * a111;
    const float dvA = wx0 * (wy0 * d00 + wy1 * d01) + wx1 * (wy0 * d10 + wy1 * d11);

    const float nzA = wx0 * (wy0 * (a001 - a000) + wy1 * (a011 - a010))
                    + wx1 * (wy0 * (a101 - a100) + wy1 * (a111 - a110));
    const float nyA = wx0 * (wz0 * (a010 - a000) + wz1 * (a011 - a001))
                    + wx1 * (wz0 * (a110 - a100) + wz1 * (a111 - a101));
    const float nxA = wy0 * (wz0 * (a100 - a000) + wz1 * (a101 - a001))
                    + wy1 * (wz0 * (a110 - a010) + wz1 * (a111 - a011));
    const float invA = 1.0f / fmaxf(sqrtf(nxA*nxA + nyA*nyA + nzA*nzA), EPSV);

    // ---------- point B ----------
    wx0 = 1.0f - fxB; wx1 = fxB;
    wy0 = 1.0f - fyB; wy1 = fyB;
    wz0 = 1.0f - fzB; wz1 = fzB;
    d00 = wz0 * b000 + wz1 * b001;
    d01 = wz0 * b010 + wz1 * b011;
    d10 = wz0 * b100 + wz1 * b101;
    d11 = wz0 * b110 + wz1 * b111;
    const float dvB = wx0 * (wy0 * d00 + wy1 * d01) + wx1 * (wy0 * d10 + wy1 * d11);

    const float nzB = wx0 * (wy0 * (b001 - b000) + wy1 * (b011 - b010))
                    + wx1 * (wy0 * (b101 - b100) + wy1 * (b111 - b110));
    const float nyB = wx0 * (wz0 * (b010 - b000) + wz1 * (b011 - b001))
                    + wx1 * (wz0 * (b110 - b100) + wz1 * (b111 - b101));
    const float nxB = wy0 * (wz0 * (b100 - b000) + wz1 * (b101 - b001))
                    + wy1 * (wz0 * (b110 - b010) + wz1 * (b111 - b011));
    const float invB = 1.0f / fmaxf(sqrtf(nxB*nxB + nyB*nyB + nzB*nzB), EPSV);

    dss[t0]       = dvA;
    dss[t0 + 256] = dvB;
    float* npA = nss + (size_t)t0 * 3;
    npA[0] = nxA * invA;
    npA[1] = nyA * invA;
    npA[2] = nzA * invA;
    float* npB = nss + (size_t)(t0 + 256) * 3;
    npB[0] = nxB * invB;
    npB[1] = nyB * invB;
    npB[2] = nzB * invB;

    float lp = fminf(dvA, 0.0f) + fminf(dvB, 0.0f);
    #pragma unroll
    for (int off = 32; off > 0; off >>= 1)
        lp += __shfl_down(lp, off, 64);
    __shared__ float wsum[4];
    const int wid = threadIdx.x >> 6;
    if ((threadIdx.x & 63) == 0) wsum[wid] = lp;
    __syncthreads();
    if (threadIdx.x == 0)
        partial[blockIdx.x] = wsum[0] + wsum[1] + wsum[2] + wsum[3];
}

// ---- Pass 2: 1024 partials -> loss = -sum (single block, no atomics) ----
__global__ __launch_bounds__(256) void loss_reduce_kernel(
    const float* __restrict__ partial, float* __restrict__ loss)
{
    const int tid = threadIdx.x;
    float s = partial[tid] + partial[tid + 256]
            + partial[tid + 512] + partial[tid + 768];
    #pragma unroll
    for (int off = 32; off > 0; off >>= 1)
        s += __shfl_down(s, off, 64);
    __shared__ float wsum[4];
    const int wid = tid >> 6;
    if ((tid & 63) == 0) wsum[wid] = s;
    __syncthreads();
    if (tid == 0)
        loss[0] = -(wsum[0] + wsum[1] + wsum[2] + wsum[3]);
}

extern "C" void kernel_launch(void* const* d_in, const int* in_sizes, int n_in,
                              void* d_out, int out_size, void* d_ws, size_t ws_size,
                              hipStream_t stream) {
    const float* pss   = (const float*)d_in[0];
    const float* grid  = (const float*)d_in[1];
    const float* first = (const float*)d_in[2];
    const float* coef  = (const float*)d_in[3];
    const float* maxl  = (const float*)d_in[4];

    float* out  = (float*)d_out;
    float* dss  = out;                          // B*N
    float* nss  = out + (size_t)BB * NN;        // B*N*3
    float* loss = out + (size_t)4 * BB * NN;    // 1

    float*    partial = (float*)d_ws;                       // NBLK floats
    unsigned* sink    = (unsigned*)((char*)d_ws + 4096);    // opaque store target

    warm_kernel<<<2048, 256, 0, stream>>>((const uint4*)grid, sink);
    tri_sdf_kernel<<<NBLK, 256, 0, stream>>>(pss, grid, first, coef, maxl,
                                             dss, nss, partial);
    loss_reduce_kernel<<<1, 256, 0, stream>>>(partial, loss);
}